// Round 10
// baseline (5817.342 us; speedup 1.0000x reference)
//
#include <hip/hip_runtime.h>

// Problem constants (match reference)
namespace {
constexpr int B = 16, N = 256, L = 4, H = 128, V = 512, OV = 1000, MAX_STEPS = 48;
constexpr int Z = 4 * H;   // 512 gate width
constexpr int BN = B * N;  // 4096 rows
constexpr int PADK = 132;  // padded LDS row stride (ushorts) to break bank aliasing
}

typedef __attribute__((ext_vector_type(8))) short short8;  // 8 bf16 (4 VGPRs)
typedef __attribute__((ext_vector_type(4))) float f32x4;   // MFMA C/D

union F8 {
    short8 s;
    uint4 u;
    uint2 h[2];
};

__device__ __forceinline__ float sigf(float x) { return 1.0f / (1.0f + __expf(-x)); }
__device__ __forceinline__ float tanh_f(float x) { return 1.0f - 2.0f / (__expf(2.0f * x) + 1.0f); }

__device__ __forceinline__ unsigned short bf16_rne(float x) {
    unsigned u = __float_as_uint(x);
    return (unsigned short)((u + 0x7fffu + ((u >> 16) & 1u)) >> 16);
}
__device__ __forceinline__ void split2(float x, unsigned short& hi, unsigned short& lo) {
    hi = bf16_rne(x);
    const float hf = __uint_as_float(((unsigned)hi) << 16);
    lo = bf16_rne(x - hf);
}

// ---------------------------------------------------------------------------
// init: zero the 4 "cur" state tensors + init ip
// ---------------------------------------------------------------------------
__global__ __launch_bounds__(256) void k_init(float4* __restrict__ cur4,
                                              float* __restrict__ ip,
                                              const int* __restrict__ start) {
    const int idx = blockIdx.x * 256 + threadIdx.x;
    cur4[idx] = make_float4(0.f, 0.f, 0.f, 0.f);
    if (idx < BN) ip[idx] = ((idx & (N - 1)) == start[idx >> 8]) ? 1.0f : 0.0f;
}

// ---------------------------------------------------------------------------
// tokz[v, :] = emb[v, :] @ Wi0 + b0   (512 x 512, K=128) -- fp32, computed once.
// ---------------------------------------------------------------------------
__global__ __launch_bounds__(256) void k_tokz(const float* __restrict__ emb,
                                              const float* __restrict__ Wi0,
                                              const float* __restrict__ b0,
                                              float* __restrict__ tokz) {
    __shared__ float lds_a[16 * 128];
    float4* l4 = (float4*)lds_a;
    const int tid = threadIdx.x;
    const int c = tid & 127, rg = tid >> 7;
    const int row0 = blockIdx.x * 16;
    {
        const float4* a4 = (const float4*)emb;
        l4[tid] = a4[row0 * 32 + tid];
        l4[tid + 256] = a4[row0 * 32 + tid + 256];
    }
    __syncthreads();
    float acc[8][4];
    {
        float bq[4];
#pragma unroll
        for (int q = 0; q < 4; q++) bq[q] = b0[c + q * 128];
#pragma unroll
        for (int i = 0; i < 8; i++)
#pragma unroll
            for (int q = 0; q < 4; q++) acc[i][q] = bq[q];
    }
    for (int k4 = 0; k4 < 32; k4++) {
        float4 a[8];
#pragma unroll
        for (int i = 0; i < 8; i++) a[i] = l4[(rg * 8 + i) * 32 + k4];
#pragma unroll
        for (int j = 0; j < 4; j++) {
            const int k = k4 * 4 + j;
            const float* wr = Wi0 + k * Z + c;
            const float w0 = wr[0], w1 = wr[128], w2 = wr[256], w3 = wr[384];
#pragma unroll
            for (int i = 0; i < 8; i++) {
                const float av = (j == 0) ? a[i].x : (j == 1) ? a[i].y : (j == 2) ? a[i].z : a[i].w;
                acc[i][0] += av * w0;
                acc[i][1] += av * w1;
                acc[i][2] += av * w2;
                acc[i][3] += av * w3;
            }
        }
    }
#pragma unroll
    for (int i = 0; i < 8; i++) {
        const int row = row0 + rg * 8 + i;
#pragma unroll
        for (int q = 0; q < 4; q++) tokz[row * Z + c + q * 128] = acc[i][q];
    }
}

// ---------------------------------------------------------------------------
// Pack weights into MFMA B-fragment order, split into bf16 hi/lo.
// Entry (mat,q,wt,ks): 64 lanes x 8 bf16; lane lp elem j holds
//   W[k][col],  k = ks*32 + ((j&4)?16:0) + (lp>>4)*4 + (j&3),
//               col = q*128 + wt*16 + (lp&15).
// Same (g,j)->k formula is used for A fragments, so the true HW k-order
// cancels (dot over k is permutation-invariant).
// ---------------------------------------------------------------------------
__global__ __launch_bounds__(256) void k_pack(const float* __restrict__ Wh0,
                                              const float* __restrict__ Wi1,
                                              const float* __restrict__ Wh1,
                                              unsigned short* __restrict__ WPhi,
                                              unsigned short* __restrict__ WPlo) {
    const int gid = blockIdx.x * 256 + threadIdx.x;
    const int lp = gid & 63;
    const int ks = (gid >> 6) & 3;
    const int w = (gid >> 8) & 7;
    const int q = (gid >> 11) & 3;
    const int split = (gid >> 13) & 1;
    const int mat = gid >> 14;  // 0..2
    const float* W = (mat == 0) ? Wh0 : (mat == 1) ? Wi1 : Wh1;
    const int g = lp >> 4, li = lp & 15;
    const int col = q * 128 + w * 16 + li;
    const int e = ((mat * 4 + q) * 8 + w) * 4 + ks;
    unsigned short* dst = (split ? WPlo : WPhi) + (size_t)e * 512 + lp * 8;
#pragma unroll
    for (int j = 0; j < 8; j++) {
        const int k = ks * 32 + ((j & 4) ? 16 : 0) + g * 4 + (j & 3);
        const float x = W[k * Z + col];
        const unsigned short hi = bf16_rne(x);
        unsigned short v = hi;
        if (split) {
            const float hf = __uint_as_float(((unsigned)hi) << 16);
            v = bf16_rne(x - hf);
        }
        dst[j] = v;
    }
}

// ---------------------------------------------------------------------------
// Build per-example CSR of dest <- (src, branch-flag). Runs once.
// ---------------------------------------------------------------------------
__global__ __launch_bounds__(256) void k_csr(const int* __restrict__ tix,
                                             const int* __restrict__ fix,
                                             int* __restrict__ off,
                                             int* __restrict__ ent) {
    const int b = blockIdx.x;
    const int m = threadIdx.x;
    __shared__ int cnt[N];
    __shared__ int wsum[4];
    cnt[m] = 0;
    __syncthreads();
    const int ti = tix[b * N + m];
    const int fi = fix[b * N + m];
    atomicAdd(&cnt[ti], 1);
    atomicAdd(&cnt[fi], 1);
    __syncthreads();
    const int v = cnt[m];
    const int lane = m & 63, w = m >> 6;
    int sc = v;
#pragma unroll
    for (int o = 1; o < 64; o <<= 1) {
        const int t = __shfl_up(sc, o);
        if (lane >= o) sc += t;
    }
    if (lane == 63) wsum[w] = sc;
    __syncthreads();
    int add = 0;
    for (int i = 0; i < w; i++) add += wsum[i];
    const int base = sc - v + add;
    off[b * (N + 1) + m] = base;
    if (m == N - 1) off[b * (N + 1) + N] = base + v;
    __syncthreads();
    cnt[m] = base;
    __syncthreads();
    const int p1 = atomicAdd(&cnt[ti], 1);
    ent[b * 2 * N + p1] = (m << 1);
    const int p2 = atomicAdd(&cnt[fi], 1);
    ent[b * 2 * N + p2] = (m << 1) | 1;
}

// ---------------------------------------------------------------------------
// Fused per-step scan, MFMA version, 4-wave geometry (spill fix).
// Block = 16 rows, 256 threads = 4 waves. Wave w owns col tiles {2w, 2w+1}
// (32 hidden cols). 256-thread blocks give the register allocator a 256-512
// VGPR budget (vs 128 for 512-thread blocks), eliminating the ~107 MB/dispatch
// scratch spill traffic seen in R3-R9 (WRITE_SIZE 115 MB vs 8 MB legit).
// ---------------------------------------------------------------------------
__global__ __launch_bounds__(256, 1) void k_scan(
    const float* __restrict__ c0c, const float* __restrict__ h0c,
    const float* __restrict__ c1c, const float* __restrict__ h1c,
    float* __restrict__ c0w, float* __restrict__ h0w,
    float* __restrict__ c1w, float* __restrict__ h1w,
    const unsigned short* __restrict__ WPhi, const unsigned short* __restrict__ WPlo,
    const float* __restrict__ b1,
    const float* __restrict__ tokz, const int* __restrict__ data,
    const float* __restrict__ bw, const float* __restrict__ bb,
    const float* __restrict__ ip, float* __restrict__ wt, float* __restrict__ wf,
    const int* __restrict__ exiti, const int* __restrict__ steps, const int s) {
    const int bx = blockIdx.x;
    const int b = bx >> 4;
    if (s >= steps[b]) return;  // per-example early exit (block-uniform)
    const int row0 = bx * 16;
    const int tid = threadIdx.x;
    const int w = tid >> 6;  // wave 0..3
    const int l = tid & 63;
    const int g = l >> 4, li = l & 15;
    const int ch0 = w * 32 + li;       // col of tile wt=2w
    const int ch1 = w * 32 + 16 + li;  // col of tile wt=2w+1

    __shared__ unsigned short h0hi[16 * PADK], h0lo[16 * PADK];
    __shared__ unsigned short h1hi[16 * PADK], h1lo[16 * PADK];
    __shared__ float red[16][4][2];

    float c0[2][4], c1[2][4], h0[2][4], h1[2][4];
#pragma unroll
    for (int w2 = 0; w2 < 2; w2++) {
        const int ch = w2 ? ch1 : ch0;
#pragma unroll
        for (int r = 0; r < 4; r++) {
            const int off = (row0 + g * 4 + r) * H + ch;
            c0[w2][r] = c0c[off];
            h0[w2][r] = h0c[off];
            c1[w2][r] = c1c[off];
            h1[w2][r] = h1c[off];
        }
    }
    float b1v[4][2];
#pragma unroll
    for (int q = 0; q < 4; q++) {
        b1v[q][0] = b1[q * 128 + ch0];
        b1v[q][1] = b1[q * 128 + ch1];
    }

    // initial h -> LDS (bf16 hi/lo)
#pragma unroll
    for (int w2 = 0; w2 < 2; w2++) {
        const int ch = w2 ? ch1 : ch0;
#pragma unroll
        for (int r = 0; r < 4; r++) {
            unsigned short hi, lo;
            split2(h0[w2][r], hi, lo);
            h0hi[(g * 4 + r) * PADK + ch] = hi;
            h0lo[(g * 4 + r) * PADK + ch] = lo;
            split2(h1[w2][r], hi, lo);
            h1hi[(g * 4 + r) * PADK + ch] = hi;
            h1lo[(g * 4 + r) * PADK + ch] = lo;
        }
    }
    __syncthreads();

#pragma unroll 1
    for (int t = 0; t < L; t++) {
        f32x4 acc[4][2];
        // ================= layer 0: z = tokz[data[:,t]] + h0 @ Wh0 ==========
        {
            int tok[4];
#pragma unroll
            for (int r = 0; r < 4; r++) tok[r] = data[(row0 + g * 4 + r) * L + t];
#pragma unroll
            for (int q = 0; q < 4; q++)
#pragma unroll
                for (int r = 0; r < 4; r++) {
                    acc[q][0][r] = tokz[tok[r] * Z + q * 128 + ch0];
                    acc[q][1][r] = tokz[tok[r] * Z + q * 128 + ch1];
                }
        }
#pragma unroll
        for (int q = 0; q < 4; q++) {
#pragma unroll
            for (int ks = 0; ks < 4; ks++) {
                F8 ahi, alo;
                const int ab = li * PADK + ks * 32 + g * 4;
                ahi.h[0] = *(const uint2*)&h0hi[ab];
                ahi.h[1] = *(const uint2*)&h0hi[ab + 16];
                alo.h[0] = *(const uint2*)&h0lo[ab];
                alo.h[1] = *(const uint2*)&h0lo[ab + 16];
#pragma unroll
                for (int w2 = 0; w2 < 2; w2++) {
                    F8 bhi, blo;
                    const int e = (q * 8 + 2 * w + w2) * 4 + ks;
                    bhi.u = *(const uint4*)(WPhi + (size_t)e * 512 + l * 8);
                    blo.u = *(const uint4*)(WPlo + (size_t)e * 512 + l * 8);
                    acc[q][w2] = __builtin_amdgcn_mfma_f32_16x16x32_bf16(ahi.s, bhi.s, acc[q][w2], 0, 0, 0);
                    acc[q][w2] = __builtin_amdgcn_mfma_f32_16x16x32_bf16(ahi.s, blo.s, acc[q][w2], 0, 0, 0);
                    acc[q][w2] = __builtin_amdgcn_mfma_f32_16x16x32_bf16(alo.s, bhi.s, acc[q][w2], 0, 0, 0);
                }
            }
            __builtin_amdgcn_sched_barrier(0);  // cap live fragment set per q-chunk
        }
#pragma unroll
        for (int w2 = 0; w2 < 2; w2++)
#pragma unroll
            for (int r = 0; r < 4; r++) {
                const float cn = sigf(acc[1][w2][r]) * c0[w2][r] + sigf(acc[0][w2][r]) * tanh_f(acc[2][w2][r]);
                c0[w2][r] = cn;
                h0[w2][r] = sigf(acc[3][w2][r]) * tanh_f(cn);
            }
        __syncthreads();  // all waves done reading h0 bufs
#pragma unroll
        for (int w2 = 0; w2 < 2; w2++) {
            const int ch = w2 ? ch1 : ch0;
#pragma unroll
            for (int r = 0; r < 4; r++) {
                unsigned short hi, lo;
                split2(h0[w2][r], hi, lo);
                h0hi[(g * 4 + r) * PADK + ch] = hi;
                h0lo[(g * 4 + r) * PADK + ch] = lo;
            }
        }
        __syncthreads();
        // ================= layer 1: z = h0new @ Wi1 + h1 @ Wh1 + b1 =========
#pragma unroll
        for (int q = 0; q < 4; q++)
#pragma unroll
            for (int w2 = 0; w2 < 2; w2++) {
                const float bv = b1v[q][w2];
                acc[q][w2][0] = bv; acc[q][w2][1] = bv; acc[q][w2][2] = bv; acc[q][w2][3] = bv;
            }
#pragma unroll
        for (int q = 0; q < 4; q++) {
#pragma unroll
            for (int ks = 0; ks < 4; ks++) {
                F8 a0hi, a0lo, a1hi, a1lo;
                const int ab = li * PADK + ks * 32 + g * 4;
                a0hi.h[0] = *(const uint2*)&h0hi[ab];
                a0hi.h[1] = *(const uint2*)&h0hi[ab + 16];
                a0lo.h[0] = *(const uint2*)&h0lo[ab];
                a0lo.h[1] = *(const uint2*)&h0lo[ab + 16];
                a1hi.h[0] = *(const uint2*)&h1hi[ab];
                a1hi.h[1] = *(const uint2*)&h1hi[ab + 16];
                a1lo.h[0] = *(const uint2*)&h1lo[ab];
                a1lo.h[1] = *(const uint2*)&h1lo[ab + 16];
#pragma unroll
                for (int w2 = 0; w2 < 2; w2++) {
                    F8 b1hi, b1lo, b2hi, b2lo;
                    const int e1 = ((4 + q) * 8 + 2 * w + w2) * 4 + ks;
                    const int e2 = ((8 + q) * 8 + 2 * w + w2) * 4 + ks;
                    b1hi.u = *(const uint4*)(WPhi + (size_t)e1 * 512 + l * 8);
                    b1lo.u = *(const uint4*)(WPlo + (size_t)e1 * 512 + l * 8);
                    b2hi.u = *(const uint4*)(WPhi + (size_t)e2 * 512 + l * 8);
                    b2lo.u = *(const uint4*)(WPlo + (size_t)e2 * 512 + l * 8);
                    acc[q][w2] = __builtin_amdgcn_mfma_f32_16x16x32_bf16(a0hi.s, b1hi.s, acc[q][w2], 0, 0, 0);
                    acc[q][w2] = __builtin_amdgcn_mfma_f32_16x16x32_bf16(a0hi.s, b1lo.s, acc[q][w2], 0, 0, 0);
                    acc[q][w2] = __builtin_amdgcn_mfma_f32_16x16x32_bf16(a0lo.s, b1hi.s, acc[q][w2], 0, 0, 0);
                    acc[q][w2] = __builtin_amdgcn_mfma_f32_16x16x32_bf16(a1hi.s, b2hi.s, acc[q][w2], 0, 0, 0);
                    acc[q][w2] = __builtin_amdgcn_mfma_f32_16x16x32_bf16(a1hi.s, b2lo.s, acc[q][w2], 0, 0, 0);
                    acc[q][w2] = __builtin_amdgcn_mfma_f32_16x16x32_bf16(a1lo.s, b2hi.s, acc[q][w2], 0, 0, 0);
                }
            }
            __builtin_amdgcn_sched_barrier(0);  // cap live fragment set per q-chunk
        }
#pragma unroll
        for (int w2 = 0; w2 < 2; w2++)
#pragma unroll
            for (int r = 0; r < 4; r++) {
                const float cn = sigf(acc[1][w2][r]) * c1[w2][r] + sigf(acc[0][w2][r]) * tanh_f(acc[2][w2][r]);
                c1[w2][r] = cn;
                h1[w2][r] = sigf(acc[3][w2][r]) * tanh_f(cn);
            }
        __syncthreads();  // all waves done reading h1 bufs
#pragma unroll
        for (int w2 = 0; w2 < 2; w2++) {
            const int ch = w2 ? ch1 : ch0;
#pragma unroll
            for (int r = 0; r < 4; r++) {
                unsigned short hi, lo;
                split2(h1[w2][r], hi, lo);
                h1hi[(g * 4 + r) * PADK + ch] = hi;
                h1lo[(g * 4 + r) * PADK + ch] = lo;
            }
        }
        __syncthreads();
    }

    // -------- exit-row patch: contrib[exit] = cur[exit] (block-uniform guard)
    const int ex = exiti[b];
    if ((ex >> 4) == (bx & 15)) {
        const int rl = ex & 15;
#pragma unroll
        for (int r = 0; r < 4; r++) {
            if (g * 4 + r == rl) {
#pragma unroll
                for (int w2 = 0; w2 < 2; w2++) {
                    const int off = (row0 + rl) * H + (w2 ? ch1 : ch0);
                    c0[w2][r] = c0c[off];
                    h0[w2][r] = h0c[off];
                    c1[w2][r] = c1c[off];
                    h1[w2][r] = h1c[off];
                }
            }
        }
    }
    // -------- store work states (read by k_agg)
#pragma unroll
    for (int w2 = 0; w2 < 2; w2++) {
        const int ch = w2 ? ch1 : ch0;
#pragma unroll
        for (int r = 0; r < 4; r++) {
            const int off = (row0 + g * 4 + r) * H + ch;
            c0w[off] = c0[w2][r];
            h0w[off] = h0[w2][r];
            c1w[off] = c1[w2][r];
            h1w[off] = h1[w2][r];
        }
    }
    // -------- branch softmax: l = concat(c0,h0,c1,h1) @ bw + bb, * ip
    float2 bwv[4][2];
#pragma unroll
    for (int x = 0; x < 4; x++) {
        bwv[x][0] = ((const float2*)bw)[x * 128 + ch0];
        bwv[x][1] = ((const float2*)bw)[x * 128 + ch1];
    }
    float l0p[4], l1p[4];
#pragma unroll
    for (int r = 0; r < 4; r++) {
        l0p[r] = 0.f;
        l1p[r] = 0.f;
#pragma unroll
        for (int w2 = 0; w2 < 2; w2++) {
            l0p[r] += c0[w2][r] * bwv[0][w2].x + h0[w2][r] * bwv[1][w2].x +
                      c1[w2][r] * bwv[2][w2].x + h1[w2][r] * bwv[3][w2].x;
            l1p[r] += c0[w2][r] * bwv[0][w2].y + h0[w2][r] * bwv[1][w2].y +
                      c1[w2][r] * bwv[2][w2].y + h1[w2][r] * bwv[3][w2].y;
        }
    }
#pragma unroll
    for (int off = 8; off > 0; off >>= 1)
#pragma unroll
        for (int r = 0; r < 4; r++) {
            l0p[r] += __shfl_xor(l0p[r], off);
            l1p[r] += __shfl_xor(l1p[r], off);
        }
    if (li == 0)
#pragma unroll
        for (int r = 0; r < 4; r++) {
            red[g * 4 + r][w][0] = l0p[r];
            red[g * 4 + r][w][1] = l1p[r];
        }
    __syncthreads();
    if (tid < 16) {
        float l0 = bb[0], l1 = bb[1];
#pragma unroll
        for (int ww = 0; ww < 4; ww++) {
            l0 += red[tid][ww][0];
            l1 += red[tid][ww][1];
        }
        const float m = fmaxf(l0, l1);
        const float e0 = __expf(l0 - m), e1 = __expf(l1 - m);
        const float inv = 1.0f / (e0 + e1);
        const float ipv = ip[row0 + tid];
        wt[row0 + tid] = e0 * inv * ipv;
        wf[row0 + tid] = e1 * inv * ipv;
    }
}

// ---------------------------------------------------------------------------
// ip redistribution + weighted state aggregation via static CSR.
// One wave per dest node; block = 4 waves, same example. grid = 1024.
// ---------------------------------------------------------------------------
__global__ __launch_bounds__(256) void k_agg(
    const float* __restrict__ c0w, const float* __restrict__ h0w,
    const float* __restrict__ c1w, const float* __restrict__ h1w,
    float* __restrict__ c0c, float* __restrict__ h0c,
    float* __restrict__ c1c, float* __restrict__ h1c,
    const int* __restrict__ off, const int* __restrict__ ent,
    const float* __restrict__ wt, const float* __restrict__ wf,
    float* __restrict__ ip, const int* __restrict__ steps, const int s) {
    const int row00 = blockIdx.x * 4;
    const int b = row00 >> 8;
    if (s >= steps[b]) return;
    const int tid = threadIdx.x;
    const int lane = tid & 63;
    const int n = (row00 & (N - 1)) + (tid >> 6);
    const int rowb = b * N;
    const int beg = off[b * (N + 1) + n];
    const int end = off[b * (N + 1) + n + 1];
    float a00 = 0, a01 = 0, a10 = 0, a11 = 0, a20 = 0, a21 = 0, a30 = 0, a31 = 0;
    float ipacc = 0.f;
    for (int e = beg; e < end; e++) {
        const int pe = ent[b * 2 * N + e];
        const int m = pe >> 1;
        const float wgt = (pe & 1) ? wf[rowb + m] : wt[rowb + m];
        ipacc += wgt;
        const int rb = (rowb + m) * H;
        a00 += c0w[rb + lane] * wgt;
        a01 += c0w[rb + lane + 64] * wgt;
        a10 += h0w[rb + lane] * wgt;
        a11 += h0w[rb + lane + 64] * wgt;
        a20 += c1w[rb + lane] * wgt;
        a21 += c1w[rb + lane + 64] * wgt;
        a30 += h1w[rb + lane] * wgt;
        a31 += h1w[rb + lane + 64] * wgt;
    }
    const float dn = 1.0f / (ipacc + 1e-7f);
    const int ob = (rowb + n) * H;
    c0c[ob + lane] = a00 * dn;
    c0c[ob + lane + 64] = a01 * dn;
    h0c[ob + lane] = a10 * dn;
    h0c[ob + lane + 64] = a11 * dn;
    c1c[ob + lane] = a20 * dn;
    c1c[ob + lane + 64] = a21 * dn;
    h1c[ob + lane] = a30 * dn;
    h1c[ob + lane + 64] = a31 * dn;
    if (lane == 0) ip[rowb + n] = ipacc;
}

// ---------------------------------------------------------------------------
// out[b, :] = h1_cur[b, exit[b], :] @ out_w + out_b
// ---------------------------------------------------------------------------
__global__ __launch_bounds__(256) void k_out(const float* __restrict__ h1c,
                                             const float* __restrict__ ow,
                                             const float* __restrict__ ob,
                                             const int* __restrict__ exiti,
                                             float* __restrict__ out) {
    const int b = blockIdx.x;
    __shared__ float h[H];
    const int tid = threadIdx.x;
    if (tid < H) h[tid] = h1c[(b * N + exiti[b]) * H + tid];
    __syncthreads();
    for (int v = tid; v < OV; v += 256) {
        float acc = ob[v];
        for (int d = 0; d < H; d++) acc += h[d] * ow[d * OV + v];
        out[b * OV + v] = acc;
    }
}

// ---------------------------------------------------------------------------
extern "C" void kernel_launch(void* const* d_in, const int* in_sizes, int n_in,
                              void* d_out, int out_size, void* d_ws, size_t ws_size,
                              hipStream_t stream) {
    (void)in_sizes; (void)n_in; (void)out_size;
    const int* data = (const int*)d_in[0];
    const int* tix = (const int*)d_in[1];
    const int* fix = (const int*)d_in[2];
    const int* start = (const int*)d_in[3];
    const int* exiti = (const int*)d_in[4];
    const int* steps = (const int*)d_in[5];
    const float* emb = (const float*)d_in[6];
    const float* Wi0 = (const float*)d_in[7];
    const float* Wh0 = (const float*)d_in[8];
    const float* b0 = (const float*)d_in[9];
    const float* Wi1 = (const float*)d_in[10];
    const float* Wh1 = (const float*)d_in[11];
    const float* b1 = (const float*)d_in[12];
    const float* bw = (const float*)d_in[13];
    const float* bb = (const float*)d_in[14];
    const float* ow = (const float*)d_in[15];
    const float* obias = (const float*)d_in[16];
    float* out = (float*)d_out;

    // workspace layout (floats)
    const size_t SB = (size_t)BN * H;  // 524288 per state tensor
    float* ws = (float*)d_ws;
    float* c0c = ws;
    float* h0c = ws + 1 * SB;
    float* c1c = ws + 2 * SB;
    float* h1c = ws + 3 * SB;
    float* c0w = ws + 4 * SB;
    float* h0w = ws + 5 * SB;
    float* c1w = ws + 6 * SB;
    float* h1w = ws + 7 * SB;
    float* tokz = ws + 8 * SB;         // V*Z = 262144
    float* ip = tokz + (size_t)V * Z;  // BN
    float* wt = ip + BN;               // BN
    float* wf = wt + BN;               // BN
    unsigned short* WPhi = (unsigned short*)(wf + BN);  // 3*65536 ushorts
    unsigned short* WPlo = WPhi + 3 * 65536;            // 3*65536 ushorts
    int* csr_off = (int*)(WPlo + 3 * 65536);            // B*(N+1)
    int* csr_ent = csr_off + B * (N + 1);               // B*2N
    const size_t need = (8 * SB + (size_t)V * Z + 3 * (size_t)BN) * sizeof(float) +
                        2 * 3 * 65536 * sizeof(unsigned short) +
                        (B * (N + 1) + B * 2 * N) * sizeof(int);
    if (ws_size < need) return;

    k_init<<<(4 * SB / 4) / 256, 256, 0, stream>>>((float4*)ws, ip, start);
    k_tokz<<<V / 16, 256, 0, stream>>>(emb, Wi0, b0, tokz);
    k_pack<<<192, 256, 0, stream>>>(Wh0, Wi1, Wh1, WPhi, WPlo);
    k_csr<<<B, 256, 0, stream>>>(tix, fix, csr_off, csr_ent);

    for (int s = 0; s < MAX_STEPS; s++) {
        k_scan<<<BN / 16, 256, 0, stream>>>(c0c, h0c, c1c, h1c, c0w, h0w, c1w, h1w,
                                            WPhi, WPlo, b1, tokz, data, bw, bb,
                                            ip, wt, wf, exiti, steps, s);
        k_agg<<<BN / 4, 256, 0, stream>>>(c0w, h0w, c1w, h1w, c0c, h0c, c1c, h1c,
                                          csr_off, csr_ent, wt, wf, ip, steps, s);
    }
    k_out<<<B, 256, 0, stream>>>(h1c, ow, obias, exiti, out);
}

// Round 11
// 4658.366 us; speedup vs baseline: 1.2488x; 1.2488x over previous
//
#include <hip/hip_runtime.h>

// Problem constants (match reference)
namespace {
constexpr int B = 16, N = 256, L = 4, H = 128, V = 512, OV = 1000, MAX_STEPS = 48;
constexpr int Z = 4 * H;   // 512 gate width
constexpr int BN = B * N;  // 4096 rows
constexpr int PADK = 132;  // padded LDS row stride (ushorts) to break bank aliasing
}

typedef __attribute__((ext_vector_type(8))) short short8;   // 8 bf16 (4 VGPRs)
typedef __attribute__((ext_vector_type(4))) short short4v;  // 8B half-fragment
typedef __attribute__((ext_vector_type(4))) float f32x4;    // MFMA C/D

__device__ __forceinline__ float sigf(float x) { return 1.0f / (1.0f + __expf(-x)); }
__device__ __forceinline__ float tanh_f(float x) { return 1.0f - 2.0f / (__expf(2.0f * x) + 1.0f); }

__device__ __forceinline__ unsigned short bf16_rne(float x) {
    unsigned u = __float_as_uint(x);
    return (unsigned short)((u + 0x7fffu + ((u >> 16) & 1u)) >> 16);
}
__device__ __forceinline__ void split2(float x, unsigned short& hi, unsigned short& lo) {
    hi = bf16_rne(x);
    const float hf = __uint_as_float(((unsigned)hi) << 16);
    lo = bf16_rne(x - hf);
}

// A-fragment: elems j=0..3 at p[0..3], j=4..7 at p[16..19] (two 8B LDS loads,
// fused to one short8 in registers -- no union, no scratch).
__device__ __forceinline__ short8 ldsA(const unsigned short* p) {
    const short4v a = *(const short4v*)p;
    const short4v b = *(const short4v*)(p + 16);
    return __builtin_shufflevector(a, b, 0, 1, 2, 3, 4, 5, 6, 7);
}

// ---------------------------------------------------------------------------
// init: zero the 4 "cur" state tensors + init ip
// ---------------------------------------------------------------------------
__global__ __launch_bounds__(256) void k_init(float4* __restrict__ cur4,
                                              float* __restrict__ ip,
                                              const int* __restrict__ start) {
    const int idx = blockIdx.x * 256 + threadIdx.x;
    cur4[idx] = make_float4(0.f, 0.f, 0.f, 0.f);
    if (idx < BN) ip[idx] = ((idx & (N - 1)) == start[idx >> 8]) ? 1.0f : 0.0f;
}

// ---------------------------------------------------------------------------
// tokz[v, :] = emb[v, :] @ Wi0 + b0   (512 x 512, K=128) -- fp32, computed once.
// ---------------------------------------------------------------------------
__global__ __launch_bounds__(256) void k_tokz(const float* __restrict__ emb,
                                              const float* __restrict__ Wi0,
                                              const float* __restrict__ b0,
                                              float* __restrict__ tokz) {
    __shared__ float lds_a[16 * 128];
    float4* l4 = (float4*)lds_a;
    const int tid = threadIdx.x;
    const int c = tid & 127, rg = tid >> 7;
    const int row0 = blockIdx.x * 16;
    {
        const float4* a4 = (const float4*)emb;
        l4[tid] = a4[row0 * 32 + tid];
        l4[tid + 256] = a4[row0 * 32 + tid + 256];
    }
    __syncthreads();
    float acc[8][4];
    {
        float bq[4];
#pragma unroll
        for (int q = 0; q < 4; q++) bq[q] = b0[c + q * 128];
#pragma unroll
        for (int i = 0; i < 8; i++)
#pragma unroll
            for (int q = 0; q < 4; q++) acc[i][q] = bq[q];
    }
    for (int k4 = 0; k4 < 32; k4++) {
        float4 a[8];
#pragma unroll
        for (int i = 0; i < 8; i++) a[i] = l4[(rg * 8 + i) * 32 + k4];
#pragma unroll
        for (int j = 0; j < 4; j++) {
            const int k = k4 * 4 + j;
            const float* wr = Wi0 + k * Z + c;
            const float w0 = wr[0], w1 = wr[128], w2 = wr[256], w3 = wr[384];
#pragma unroll
            for (int i = 0; i < 8; i++) {
                const float av = (j == 0) ? a[i].x : (j == 1) ? a[i].y : (j == 2) ? a[i].z : a[i].w;
                acc[i][0] += av * w0;
                acc[i][1] += av * w1;
                acc[i][2] += av * w2;
                acc[i][3] += av * w3;
            }
        }
    }
#pragma unroll
    for (int i = 0; i < 8; i++) {
        const int row = row0 + rg * 8 + i;
#pragma unroll
        for (int q = 0; q < 4; q++) tokz[row * Z + c + q * 128] = acc[i][q];
    }
}

// ---------------------------------------------------------------------------
// Pack weights into MFMA B-fragment order, split into bf16 hi/lo.
// Entry (mat,q,w,ks): 64 lanes x 8 bf16; lane lp elem j holds
//   W[k][col],  k = ks*32 + ((j&4)?16:0) + (lp>>4)*4 + (j&3),
//               col = q*128 + w*16 + (lp&15).
// Same (g,j)->k formula is used for A fragments, so the true HW k-order
// cancels (dot over k is permutation-invariant).
// ---------------------------------------------------------------------------
__global__ __launch_bounds__(256) void k_pack(const float* __restrict__ Wh0,
                                              const float* __restrict__ Wi1,
                                              const float* __restrict__ Wh1,
                                              unsigned short* __restrict__ WPhi,
                                              unsigned short* __restrict__ WPlo) {
    const int gid = blockIdx.x * 256 + threadIdx.x;
    const int lp = gid & 63;
    const int ks = (gid >> 6) & 3;
    const int w = (gid >> 8) & 7;
    const int q = (gid >> 11) & 3;
    const int split = (gid >> 13) & 1;
    const int mat = gid >> 14;  // 0..2
    const float* W = (mat == 0) ? Wh0 : (mat == 1) ? Wi1 : Wh1;
    const int g = lp >> 4, li = lp & 15;
    const int col = q * 128 + w * 16 + li;
    const int e = ((mat * 4 + q) * 8 + w) * 4 + ks;
    unsigned short* dst = (split ? WPlo : WPhi) + (size_t)e * 512 + lp * 8;
#pragma unroll
    for (int j = 0; j < 8; j++) {
        const int k = ks * 32 + ((j & 4) ? 16 : 0) + g * 4 + (j & 3);
        const float x = W[k * Z + col];
        const unsigned short hi = bf16_rne(x);
        unsigned short v = hi;
        if (split) {
            const float hf = __uint_as_float(((unsigned)hi) << 16);
            v = bf16_rne(x - hf);
        }
        dst[j] = v;
    }
}

// ---------------------------------------------------------------------------
// Build per-example CSR of dest <- (src, branch-flag). Runs once.
// ---------------------------------------------------------------------------
__global__ __launch_bounds__(256) void k_csr(const int* __restrict__ tix,
                                             const int* __restrict__ fix,
                                             int* __restrict__ off,
                                             int* __restrict__ ent) {
    const int b = blockIdx.x;
    const int m = threadIdx.x;
    __shared__ int cnt[N];
    __shared__ int wsum[4];
    cnt[m] = 0;
    __syncthreads();
    const int ti = tix[b * N + m];
    const int fi = fix[b * N + m];
    atomicAdd(&cnt[ti], 1);
    atomicAdd(&cnt[fi], 1);
    __syncthreads();
    const int v = cnt[m];
    const int lane = m & 63, w = m >> 6;
    int sc = v;
#pragma unroll
    for (int o = 1; o < 64; o <<= 1) {
        const int t = __shfl_up(sc, o);
        if (lane >= o) sc += t;
    }
    if (lane == 63) wsum[w] = sc;
    __syncthreads();
    int add = 0;
    for (int i = 0; i < w; i++) add += wsum[i];
    const int base = sc - v + add;
    off[b * (N + 1) + m] = base;
    if (m == N - 1) off[b * (N + 1) + N] = base + v;
    __syncthreads();
    cnt[m] = base;
    __syncthreads();
    const int p1 = atomicAdd(&cnt[ti], 1);
    ent[b * 2 * N + p1] = (m << 1);
    const int p2 = atomicAdd(&cnt[fi], 1);
    ent[b * 2 * N + p2] = (m << 1) | 1;
}

// ---------------------------------------------------------------------------
// Fused per-step scan, MFMA version (R7 geometry), union-free fragments.
// Block = 16 rows, 512 threads = 8 waves. Wave w owns cols {q*128 + w*16 + li}.
// All A/B fragments are pure vector loads / shufflevector SSA values --
// no union type-punning (suspected scratch source of the 106 MB/dispatch
// excess WRITE constant across R3-R10).
// ---------------------------------------------------------------------------
__global__ __launch_bounds__(512) void k_scan(
    const float* __restrict__ c0c, const float* __restrict__ h0c,
    const float* __restrict__ c1c, const float* __restrict__ h1c,
    float* __restrict__ c0w, float* __restrict__ h0w,
    float* __restrict__ c1w, float* __restrict__ h1w,
    const unsigned short* __restrict__ WPhi, const unsigned short* __restrict__ WPlo,
    const float* __restrict__ b1,
    const float* __restrict__ tokz, const int* __restrict__ data,
    const float* __restrict__ bw, const float* __restrict__ bb,
    const float* __restrict__ ip, float* __restrict__ wt, float* __restrict__ wf,
    const int* __restrict__ exiti, const int* __restrict__ steps, const int s) {
    const int bx = blockIdx.x;
    const int b = bx >> 4;
    if (s >= steps[b]) return;  // per-example early exit (block-uniform)
    const int row0 = bx * 16;
    const int tid = threadIdx.x;
    const int w = tid >> 6;
    const int l = tid & 63;
    const int g = l >> 4, li = l & 15;
    const int ch = w * 16 + li;  // hidden col 0..127

    __shared__ unsigned short h0hi[16 * PADK], h0lo[16 * PADK];
    __shared__ unsigned short h1hi[16 * PADK], h1lo[16 * PADK];
    __shared__ float red[16][8][2];

    float c0[4], c1[4], h0[4], h1[4];
#pragma unroll
    for (int r = 0; r < 4; r++) {
        const int off = (row0 + g * 4 + r) * H + ch;
        c0[r] = c0c[off];
        h0[r] = h0c[off];
        c1[r] = c1c[off];
        h1[r] = h1c[off];
    }
    float b1v[4];
#pragma unroll
    for (int q = 0; q < 4; q++) b1v[q] = b1[q * 128 + ch];

    // initial h -> LDS (bf16 hi/lo)
#pragma unroll
    for (int r = 0; r < 4; r++) {
        unsigned short hi, lo;
        split2(h0[r], hi, lo);
        h0hi[(g * 4 + r) * PADK + ch] = hi;
        h0lo[(g * 4 + r) * PADK + ch] = lo;
        split2(h1[r], hi, lo);
        h1hi[(g * 4 + r) * PADK + ch] = hi;
        h1lo[(g * 4 + r) * PADK + ch] = lo;
    }
    __syncthreads();

#pragma unroll 1
    for (int t = 0; t < L; t++) {
        f32x4 acc[4];
        // ================= layer 0: z = tokz[data[:,t]] + h0 @ Wh0 ==========
        {
            int tok[4];
#pragma unroll
            for (int r = 0; r < 4; r++) tok[r] = data[(row0 + g * 4 + r) * L + t];
#pragma unroll
            for (int q = 0; q < 4; q++)
#pragma unroll
                for (int r = 0; r < 4; r++) acc[q][r] = tokz[tok[r] * Z + q * 128 + ch];
        }
#pragma unroll
        for (int q = 0; q < 4; q++) {
#pragma unroll
            for (int ks = 0; ks < 4; ks++) {
                const int ab = li * PADK + ks * 32 + g * 4;
                const short8 ahi = ldsA(&h0hi[ab]);
                const short8 alo = ldsA(&h0lo[ab]);
                const int e = (q * 8 + w) * 4 + ks;
                const short8 bhi = *(const short8*)(WPhi + (size_t)e * 512 + l * 8);
                const short8 blo = *(const short8*)(WPlo + (size_t)e * 512 + l * 8);
                acc[q] = __builtin_amdgcn_mfma_f32_16x16x32_bf16(ahi, bhi, acc[q], 0, 0, 0);
                acc[q] = __builtin_amdgcn_mfma_f32_16x16x32_bf16(ahi, blo, acc[q], 0, 0, 0);
                acc[q] = __builtin_amdgcn_mfma_f32_16x16x32_bf16(alo, bhi, acc[q], 0, 0, 0);
            }
            __builtin_amdgcn_sched_barrier(0);  // cap live fragment set per q-chunk
        }
#pragma unroll
        for (int r = 0; r < 4; r++) {
            const float cn = sigf(acc[1][r]) * c0[r] + sigf(acc[0][r]) * tanh_f(acc[2][r]);
            c0[r] = cn;
            h0[r] = sigf(acc[3][r]) * tanh_f(cn);
        }
        __syncthreads();  // all waves done reading h0 bufs
#pragma unroll
        for (int r = 0; r < 4; r++) {
            unsigned short hi, lo;
            split2(h0[r], hi, lo);
            h0hi[(g * 4 + r) * PADK + ch] = hi;
            h0lo[(g * 4 + r) * PADK + ch] = lo;
        }
        __syncthreads();
        // ================= layer 1: z = h0new @ Wi1 + h1 @ Wh1 + b1 =========
#pragma unroll
        for (int q = 0; q < 4; q++) {
            const float bv = b1v[q];
            acc[q][0] = bv; acc[q][1] = bv; acc[q][2] = bv; acc[q][3] = bv;
        }
#pragma unroll
        for (int q = 0; q < 4; q++) {
#pragma unroll
            for (int ks = 0; ks < 4; ks++) {
                const int ab = li * PADK + ks * 32 + g * 4;
                const short8 a0hi = ldsA(&h0hi[ab]);
                const short8 a0lo = ldsA(&h0lo[ab]);
                const short8 a1hi = ldsA(&h1hi[ab]);
                const short8 a1lo = ldsA(&h1lo[ab]);
                const int e1 = ((4 + q) * 8 + w) * 4 + ks;
                const int e2 = ((8 + q) * 8 + w) * 4 + ks;
                const short8 b1hi = *(const short8*)(WPhi + (size_t)e1 * 512 + l * 8);
                const short8 b1lo = *(const short8*)(WPlo + (size_t)e1 * 512 + l * 8);
                const short8 b2hi = *(const short8*)(WPhi + (size_t)e2 * 512 + l * 8);
                const short8 b2lo = *(const short8*)(WPlo + (size_t)e2 * 512 + l * 8);
                acc[q] = __builtin_amdgcn_mfma_f32_16x16x32_bf16(a0hi, b1hi, acc[q], 0, 0, 0);
                acc[q] = __builtin_amdgcn_mfma_f32_16x16x32_bf16(a0hi, b1lo, acc[q], 0, 0, 0);
                acc[q] = __builtin_amdgcn_mfma_f32_16x16x32_bf16(a0lo, b1hi, acc[q], 0, 0, 0);
                acc[q] = __builtin_amdgcn_mfma_f32_16x16x32_bf16(a1hi, b2hi, acc[q], 0, 0, 0);
                acc[q] = __builtin_amdgcn_mfma_f32_16x16x32_bf16(a1hi, b2lo, acc[q], 0, 0, 0);
                acc[q] = __builtin_amdgcn_mfma_f32_16x16x32_bf16(a1lo, b2hi, acc[q], 0, 0, 0);
            }
            __builtin_amdgcn_sched_barrier(0);  // cap live fragment set per q-chunk
        }
#pragma unroll
        for (int r = 0; r < 4; r++) {
            const float cn = sigf(acc[1][r]) * c1[r] + sigf(acc[0][r]) * tanh_f(acc[2][r]);
            c1[r] = cn;
            h1[r] = sigf(acc[3][r]) * tanh_f(cn);
        }
        __syncthreads();  // all waves done reading h1 bufs
#pragma unroll
        for (int r = 0; r < 4; r++) {
            unsigned short hi, lo;
            split2(h1[r], hi, lo);
            h1hi[(g * 4 + r) * PADK + ch] = hi;
            h1lo[(g * 4 + r) * PADK + ch] = lo;
        }
        __syncthreads();
    }

    // -------- exit-row patch: contrib[exit] = cur[exit] (block-uniform guard)
    const int ex = exiti[b];
    if ((ex >> 4) == (bx & 15)) {
        const int rl = ex & 15;
#pragma unroll
        for (int r = 0; r < 4; r++) {
            if (g * 4 + r == rl) {
                const int off = (row0 + rl) * H + ch;
                c0[r] = c0c[off];
                h0[r] = h0c[off];
                c1[r] = c1c[off];
                h1[r] = h1c[off];
            }
        }
    }
    // -------- store work states (read by k_agg)
#pragma unroll
    for (int r = 0; r < 4; r++) {
        const int off = (row0 + g * 4 + r) * H + ch;
        c0w[off] = c0[r];
        h0w[off] = h0[r];
        c1w[off] = c1[r];
        h1w[off] = h1[r];
    }
    // -------- branch softmax: l = concat(c0,h0,c1,h1) @ bw + bb, * ip
    float2 bwv[4];
#pragma unroll
    for (int x = 0; x < 4; x++) bwv[x] = ((const float2*)bw)[x * 128 + ch];
    float l0p[4], l1p[4];
#pragma unroll
    for (int r = 0; r < 4; r++) {
        l0p[r] = c0[r] * bwv[0].x + h0[r] * bwv[1].x + c1[r] * bwv[2].x + h1[r] * bwv[3].x;
        l1p[r] = c0[r] * bwv[0].y + h0[r] * bwv[1].y + c1[r] * bwv[2].y + h1[r] * bwv[3].y;
    }
#pragma unroll
    for (int off = 8; off > 0; off >>= 1)
#pragma unroll
        for (int r = 0; r < 4; r++) {
            l0p[r] += __shfl_xor(l0p[r], off);
            l1p[r] += __shfl_xor(l1p[r], off);
        }
    if (li == 0)
#pragma unroll
        for (int r = 0; r < 4; r++) {
            red[g * 4 + r][w][0] = l0p[r];
            red[g * 4 + r][w][1] = l1p[r];
        }
    __syncthreads();
    if (tid < 16) {
        float l0 = bb[0], l1 = bb[1];
#pragma unroll
        for (int ww = 0; ww < 8; ww++) {
            l0 += red[tid][ww][0];
            l1 += red[tid][ww][1];
        }
        const float m = fmaxf(l0, l1);
        const float e0 = __expf(l0 - m), e1 = __expf(l1 - m);
        const float inv = 1.0f / (e0 + e1);
        const float ipv = ip[row0 + tid];
        wt[row0 + tid] = e0 * inv * ipv;
        wf[row0 + tid] = e1 * inv * ipv;
    }
}

// ---------------------------------------------------------------------------
// ip redistribution + weighted state aggregation via static CSR.
// One wave per dest node; block = 4 waves, same example. grid = 1024.
// ---------------------------------------------------------------------------
__global__ __launch_bounds__(256) void k_agg(
    const float* __restrict__ c0w, const float* __restrict__ h0w,
    const float* __restrict__ c1w, const float* __restrict__ h1w,
    float* __restrict__ c0c, float* __restrict__ h0c,
    float* __restrict__ c1c, float* __restrict__ h1c,
    const int* __restrict__ off, const int* __restrict__ ent,
    const float* __restrict__ wt, const float* __restrict__ wf,
    float* __restrict__ ip, const int* __restrict__ steps, const int s) {
    const int row00 = blockIdx.x * 4;
    const int b = row00 >> 8;
    if (s >= steps[b]) return;
    const int tid = threadIdx.x;
    const int lane = tid & 63;
    const int n = (row00 & (N - 1)) + (tid >> 6);
    const int rowb = b * N;
    const int beg = off[b * (N + 1) + n];
    const int end = off[b * (N + 1) + n + 1];
    float a00 = 0, a01 = 0, a10 = 0, a11 = 0, a20 = 0, a21 = 0, a30 = 0, a31 = 0;
    float ipacc = 0.f;
    for (int e = beg; e < end; e++) {
        const int pe = ent[b * 2 * N + e];
        const int m = pe >> 1;
        const float wgt = (pe & 1) ? wf[rowb + m] : wt[rowb + m];
        ipacc += wgt;
        const int rb = (rowb + m) * H;
        a00 += c0w[rb + lane] * wgt;
        a01 += c0w[rb + lane + 64] * wgt;
        a10 += h0w[rb + lane] * wgt;
        a11 += h0w[rb + lane + 64] * wgt;
        a20 += c1w[rb + lane] * wgt;
        a21 += c1w[rb + lane + 64] * wgt;
        a30 += h1w[rb + lane] * wgt;
        a31 += h1w[rb + lane + 64] * wgt;
    }
    const float dn = 1.0f / (ipacc + 1e-7f);
    const int ob = (rowb + n) * H;
    c0c[ob + lane] = a00 * dn;
    c0c[ob + lane + 64] = a01 * dn;
    h0c[ob + lane] = a10 * dn;
    h0c[ob + lane + 64] = a11 * dn;
    c1c[ob + lane] = a20 * dn;
    c1c[ob + lane + 64] = a21 * dn;
    h1c[ob + lane] = a30 * dn;
    h1c[ob + lane + 64] = a31 * dn;
    if (lane == 0) ip[rowb + n] = ipacc;
}

// ---------------------------------------------------------------------------
// out[b, :] = h1_cur[b, exit[b], :] @ out_w + out_b
// ---------------------------------------------------------------------------
__global__ __launch_bounds__(256) void k_out(const float* __restrict__ h1c,
                                             const float* __restrict__ ow,
                                             const float* __restrict__ ob,
                                             const int* __restrict__ exiti,
                                             float* __restrict__ out) {
    const int b = blockIdx.x;
    __shared__ float h[H];
    const int tid = threadIdx.x;
    if (tid < H) h[tid] = h1c[(b * N + exiti[b]) * H + tid];
    __syncthreads();
    for (int v = tid; v < OV; v += 256) {
        float acc = ob[v];
        for (int d = 0; d < H; d++) acc += h[d] * ow[d * OV + v];
        out[b * OV + v] = acc;
    }
}

// ---------------------------------------------------------------------------
extern "C" void kernel_launch(void* const* d_in, const int* in_sizes, int n_in,
                              void* d_out, int out_size, void* d_ws, size_t ws_size,
                              hipStream_t stream) {
    (void)in_sizes; (void)n_in; (void)out_size;
    const int* data = (const int*)d_in[0];
    const int* tix = (const int*)d_in[1];
    const int* fix = (const int*)d_in[2];
    const int* start = (const int*)d_in[3];
    const int* exiti = (const int*)d_in[4];
    const int* steps = (const int*)d_in[5];
    const float* emb = (const float*)d_in[6];
    const float* Wi0 = (const float*)d_in[7];
    const float* Wh0 = (const float*)d_in[8];
    const float* b0 = (const float*)d_in[9];
    const float* Wi1 = (const float*)d_in[10];
    const float* Wh1 = (const float*)d_in[11];
    const float* b1 = (const float*)d_in[12];
    const float* bw = (const float*)d_in[13];
    const float* bb = (const float*)d_in[14];
    const float* ow = (const float*)d_in[15];
    const float* obias = (const float*)d_in[16];
    float* out = (float*)d_out;

    // workspace layout (floats)
    const size_t SB = (size_t)BN * H;  // 524288 per state tensor
    float* ws = (float*)d_ws;
    float* c0c = ws;
    float* h0c = ws + 1 * SB;
    float* c1c = ws + 2 * SB;
    float* h1c = ws + 3 * SB;
    float* c0w = ws + 4 * SB;
    float* h0w = ws + 5 * SB;
    float* c1w = ws + 6 * SB;
    float* h1w = ws + 7 * SB;
    float* tokz = ws + 8 * SB;         // V*Z = 262144
    float* ip = tokz + (size_t)V * Z;  // BN
    float* wt = ip + BN;               // BN
    float* wf = wt + BN;               // BN
    unsigned short* WPhi = (unsigned short*)(wf + BN);  // 3*65536 ushorts
    unsigned short* WPlo = WPhi + 3 * 65536;            // 3*65536 ushorts
    int* csr_off = (int*)(WPlo + 3 * 65536);            // B*(N+1)
    int* csr_ent = csr_off + B * (N + 1);               // B*2N
    const size_t need = (8 * SB + (size_t)V * Z + 3 * (size_t)BN) * sizeof(float) +
                        2 * 3 * 65536 * sizeof(unsigned short) +
                        (B * (N + 1) + B * 2 * N) * sizeof(int);
    if (ws_size < need) return;

    k_init<<<(4 * SB / 4) / 256, 256, 0, stream>>>((float4*)ws, ip, start);
    k_tokz<<<V / 16, 256, 0, stream>>>(emb, Wi0, b0, tokz);
    k_pack<<<192, 256, 0, stream>>>(Wh0, Wi1, Wh1, WPhi, WPlo);
    k_csr<<<B, 256, 0, stream>>>(tix, fix, csr_off, csr_ent);

    for (int s = 0; s < MAX_STEPS; s++) {
        k_scan<<<BN / 16, 512, 0, stream>>>(c0c, h0c, c1c, h1c, c0w, h0w, c1w, h1w,
                                            WPhi, WPlo, b1, tokz, data, bw, bb,
                                            ip, wt, wf, exiti, steps, s);
        k_agg<<<BN / 4, 256, 0, stream>>>(c0w, h0w, c1w, h1w, c0c, h0c, c1c, h1c,
                                          csr_off, csr_ent, wt, wf, ip, steps, s);
    }
    k_out<<<B, 256, 0, stream>>>(h1c, ow, obias, exiti, out);
}